// Round 13
// baseline (6367.463 us; speedup 1.0000x reference)
//
#include <hip/hip_runtime.h>
#include <math.h>

// QLinear via int8: y = (sum_k xq[r][k]*Wq[c][k]) * sx[r] * scale[c]
// Wq in [0,16) is EXACT in i8; only x-quantization contributes error.
#define M_DIM 8192    // BATCH*SEQ
#define N_DIM 11008   // OUT_F
#define K_DIM 4096    // IN_F

#define BM 256
#define BN 256
#define BKB 64                     // K-bytes per tile (64 i8)
#define NT (K_DIM / BKB)           // 64 K-tiles
#define NBN (N_DIM / BN)           // 43
#define NWG ((M_DIM / BM) * NBN)   // 1376 (divisible by 8)

// LDS per buffer: A 256x64B = 16 KiB, B 256x64B = 16 KiB -> 32 KiB; x2 = 64 KiB.
// 2 blocks/CU (128 KiB LDS total, 16 waves).
#define BUF_STRIDE 32768
#define B_OFF 16384

typedef int int4v __attribute__((ext_vector_type(4)));
typedef int int16v __attribute__((ext_vector_type(16)));

__device__ __forceinline__ void async_copy16(const void* g, void* l) {
  __builtin_amdgcn_global_load_lds(
      (const __attribute__((address_space(1))) void*)g,
      (__attribute__((address_space(3))) void*)l, 16, 0, 0);
}

// ---- x quantization: one block per row; per-row absmax -> i8 ----
__global__ __launch_bounds__(256) void quant_x(const float* __restrict__ x,
                                               signed char* __restrict__ xq,
                                               float* __restrict__ sx) {
  __shared__ float wred[4];
  const int row = blockIdx.x;
  const int tid = threadIdx.x;
  const float4* src = (const float4*)(x + (size_t)row * K_DIM) + tid * 4;
  float4 v0 = src[0], v1 = src[1], v2 = src[2], v3 = src[3];

  float m = 0.f;
#define MX4(V) m = fmaxf(m, fmaxf(fmaxf(fabsf(V.x), fabsf(V.y)), fmaxf(fabsf(V.z), fabsf(V.w))))
  MX4(v0); MX4(v1); MX4(v2); MX4(v3);
#undef MX4
#pragma unroll
  for (int off = 32; off >= 1; off >>= 1)
    m = fmaxf(m, __shfl_xor(m, off, 64));
  if ((tid & 63) == 0) wred[tid >> 6] = m;
  __syncthreads();
  float smax = fmaxf(fmaxf(wred[0], wred[1]), fmaxf(wred[2], wred[3]));
  smax = fmaxf(smax, 1e-20f);
  const float inv = 127.f / smax;

  int4v o;
#define Q4(V, G) o[G] = ((int)rintf(V.x * inv) & 255) | (((int)rintf(V.y * inv) & 255) << 8) | \
                        (((int)rintf(V.z * inv) & 255) << 16) | (((int)rintf(V.w * inv) & 255) << 24)
  Q4(v0, 0); Q4(v1, 1); Q4(v2, 2); Q4(v3, 3);
#undef Q4
  ((int4v*)(xq + (size_t)row * K_DIM))[tid] = o;
  if (tid == 0) sx[row] = smax / 127.f;
}

// ---- W pack: int32 (0..15) -> i8, 16 elems/thread ----
__global__ __launch_bounds__(256) void pack_w(const int* __restrict__ in,
                                              signed char* __restrict__ wq) {
  const int idx = blockIdx.x * 256 + threadIdx.x;
  const int4* in4 = (const int4*)in + (size_t)idx * 4;
  int4 a = in4[0], b = in4[1], c = in4[2], d = in4[3];
  int4v o;
  o[0] = a.x | (a.y << 8) | (a.z << 16) | (a.w << 24);
  o[1] = b.x | (b.y << 8) | (b.z << 16) | (b.w << 24);
  o[2] = c.x | (c.y << 8) | (c.z << 16) | (c.w << 24);
  o[3] = d.x | (d.y << 8) | (d.z << 16) | (d.w << 24);
  ((int4v*)wq)[idx] = o;
}

// Stage one 128x64B group (8 KiB): linear LDS dest, inverse-swizzled global
// source. key(r) = ((r>>1)^(r>>3))&3 on the 16B-chunk index; grow0 is a
// multiple of 128 so key depends only on rl. 1 gload_lds/thread.
__device__ __forceinline__ void stage_q(const signed char* __restrict__ P,
                                        int grow0, int k0b, char* dest, int tid) {
  const int rl = tid >> 2;                           // 0..127
  const int key = ((rl >> 1) ^ (rl >> 3)) & 3;
  const int kb = (((tid & 3) ^ key) << 4);           // pre-swizzled chunk byte
  async_copy16(&P[(size_t)(grow0 + rl) * K_DIM + k0b + kb], dest + tid * 16);
}

// ---- main GEMM: 256x256 block-tile, BKB=64, 8 waves (2x4, 128x64/wave),
// i8 MFMA, 64 KiB LDS => 2 blocks/CU. 128x64 wave-tile cuts LDS work to
// 0.75 b128-reads + 250 stage-bytes per MFMA (R12: 1.0 + 375) — the LDS
// pipe is the measured wall. R5 sync skeleton unchanged. ----
// C/D: col=lane&31, row=(reg&3)+8*(reg>>2)+4*(lane>>5) [m74/m101; R9-R12 HW-ok].
__global__ __launch_bounds__(512, 4) void gemm_i8(
    const signed char* __restrict__ A, const signed char* __restrict__ B,
    const float* __restrict__ scale, const float* __restrict__ sx,
    float* __restrict__ out) {
  __shared__ __align__(16) char smw[2 * BUF_STRIDE];  // 64 KiB
  const int tid = threadIdx.x;
  const int lane = tid & 63;
  const int wv = tid >> 6;
  const int wr = wv >> 2, wc = wv & 3;   // 2x4 wave grid, 128x64 out/wave
  const int l31 = lane & 31;
  const int h = lane >> 5;
  const int swz = ((((l31 >> 1) ^ (l31 >> 3)) & 3) << 4);  // lane-only key

  int id = blockIdx.x;                   // T1: bijective XCD swizzle
  id = (id & 7) * (NWG / 8) + (id >> 3);
  const int bn = (id % NBN) * BN;
  const int bm = (id / NBN) * BM;

  int16v acc[4][2] = {};                 // 128 accum regs

  // prologue: stage tile 0 (4 issues); vmcnt BEFORE barrier (visibility)
  stage_q(A, bm,       0, smw,                 tid);
  stage_q(A, bm + 128, 0, smw + 8192,          tid);
  stage_q(B, bn,       0, smw + B_OFF,         tid);
  stage_q(B, bn + 128, 0, smw + B_OFF + 8192,  tid);
  asm volatile("s_waitcnt vmcnt(0)" ::: "memory");
  __builtin_amdgcn_s_barrier();

#pragma unroll 1
  for (int t = 0; t < NT; ++t) {
    const int cur = t & 1;
    const char* Abuf = smw + cur * BUF_STRIDE + wr * 8192;   // wave's 128 A-rows
    const char* Bbuf = smw + cur * BUF_STRIDE + B_OFF + (wc >> 1) * 8192;
    char* nb = smw + (cur ^ 1) * BUF_STRIDE;
    const int k1 = (t + 1) * BKB;
    const bool pf = (t + 1 < NT);

    // 2 K-halves; 6 ds_read_b128 + 8 MFMA each; prefetch spread across them
#pragma unroll
    for (int kq = 0; kq < 2; ++kq) {
      const int cb = ((kq * 2 + h) << 4) ^ swz;
      int4v af[4], bfr[2];
#pragma unroll
      for (int mi = 0; mi < 4; ++mi)
        af[mi] = *(const int4v*)(Abuf + (mi * 32 + l31) * 64 + cb);
#pragma unroll
      for (int ni = 0; ni < 2; ++ni)
        bfr[ni] = *(const int4v*)(Bbuf + ((wc & 1) * 64 + ni * 32 + l31) * 64 + cb);
      if (pf) {
        if (kq == 0) {
          stage_q(A, bm,       k1, nb,        tid);
          stage_q(A, bm + 128, k1, nb + 8192, tid);
        } else {
          stage_q(B, bn,       k1, nb + B_OFF,        tid);
          stage_q(B, bn + 128, k1, nb + B_OFF + 8192, tid);
        }
      }
      __builtin_amdgcn_s_setprio(1);
#pragma unroll
      for (int mi = 0; mi < 4; ++mi)
#pragma unroll
        for (int ni = 0; ni < 2; ++ni)
          acc[mi][ni] = __builtin_amdgcn_mfma_i32_32x32x32_i8(
              af[mi], bfr[ni], acc[mi][ni], 0, 0, 0);
      __builtin_amdgcn_s_setprio(0);
    }

    // Bottom sync: drain own prefetch, THEN barrier (cross-wave visibility).
    // Drain gap covered by the co-resident block's compute (R12-verified).
    if (pf) {
      asm volatile("s_waitcnt vmcnt(0)" ::: "memory");
      __builtin_amdgcn_s_barrier();
    }
  }

  // epilogue: y = acc * sx[row] * scale[col]; 32x32 C/D layout
  const int ocol0 = bn + wc * 64 + l31;
  const int orow0 = bm + wr * 128 + 4 * h;
#pragma unroll
  for (int ni = 0; ni < 2; ++ni) {
    const float sc = scale[ocol0 + ni * 32];
#pragma unroll
    for (int mi = 0; mi < 4; ++mi) {
#pragma unroll
      for (int reg = 0; reg < 16; ++reg) {
        const int row = orow0 + mi * 32 + (reg & 3) + 8 * (reg >> 2);
        out[(size_t)row * N_DIM + ocol0 + ni * 32] =
            (float)acc[mi][ni][reg] * sx[row] * sc;
      }
    }
  }
}

// ---- fallback (only if ws too small): fp32 LDS-tiled, correct but slow ----
__global__ __launch_bounds__(256) void gemm_fallback(
    const float* __restrict__ X, const int* __restrict__ Wq,
    const float* __restrict__ scale, float* __restrict__ out) {
  __shared__ float Xs[64][17];
  __shared__ float Ws[64][17];
  const int tid = threadIdx.x;
  const int tn = blockIdx.x % (N_DIM / 64);
  const int tm = blockIdx.x / (N_DIM / 64);
  const int tr = tid >> 4, tc = tid & 15;
  float acc[4][4] = {};
  for (int k0 = 0; k0 < K_DIM; k0 += 16) {
#pragma unroll
    for (int i = 0; i < 4; ++i) {
      int idx = tid + i * 256;
      int r = idx >> 4, c = idx & 15;
      Xs[r][c] = X[(size_t)(tm * 64 + r) * K_DIM + k0 + c];
      Ws[r][c] = (float)Wq[(size_t)(tn * 64 + r) * K_DIM + k0 + c];
    }
    __syncthreads();
#pragma unroll
    for (int kk = 0; kk < 16; ++kk)
#pragma unroll
      for (int i = 0; i < 4; ++i) {
        float a = Xs[tr * 4 + i][kk];
#pragma unroll
        for (int j = 0; j < 4; ++j) acc[i][j] += a * Ws[tc * 4 + j][kk];
      }
    __syncthreads();
  }
#pragma unroll
  for (int i = 0; i < 4; ++i)
#pragma unroll
    for (int j = 0; j < 4; ++j) {
      int row = tm * 64 + tr * 4 + i, col = tn * 64 + tc * 4 + j;
      out[(size_t)row * N_DIM + col] = acc[i][j] * scale[col];
    }
}

extern "C" void kernel_launch(void* const* d_in, const int* in_sizes, int n_in,
                              void* d_out, int out_size, void* d_ws, size_t ws_size,
                              hipStream_t stream) {
  const float* x = (const float*)d_in[0];
  const int* Wq = (const int*)d_in[1];
  const float* scale = (const float*)d_in[2];
  float* out = (float*)d_out;

  const size_t XN = (size_t)M_DIM * K_DIM;   // 33,554,432
  const size_t WN = (size_t)N_DIM * K_DIM;   // 45,088,768
  const size_t need = XN + WN + M_DIM * sizeof(float);

  if (ws_size >= need) {
    signed char* xq = (signed char*)d_ws;
    signed char* wq = xq + XN;
    float* sx = (float*)(wq + WN);
    quant_x<<<M_DIM, 256, 0, stream>>>(x, xq, sx);
    pack_w<<<(unsigned)(WN / 4096), 256, 0, stream>>>(Wq, wq);
    gemm_i8<<<NWG, 512, 0, stream>>>(xq, wq, scale, sx, out);
  } else {
    gemm_fallback<<<(N_DIM / 64) * (M_DIM / 64), 256, 0, stream>>>(x, Wq, scale, out);
  }
}

// Round 14
// 515.291 us; speedup vs baseline: 12.3570x; 12.3570x over previous
//
#include <hip/hip_runtime.h>
#include <math.h>

// QLinear via int8: y = (sum_k xq[r][k]*Wq[c][k]) * sx[r] * scale[c]
// Wq in [0,16) is EXACT in i8; only x-quantization contributes error.
#define M_DIM 8192    // BATCH*SEQ
#define N_DIM 11008   // OUT_F
#define K_DIM 4096    // IN_F

#define BM 256
#define BN 256
#define BKB 64                     // K-bytes per tile (64 i8)
#define NT (K_DIM / BKB)           // 64 K-tiles
#define NBN (N_DIM / BN)           // 43
#define NWG ((M_DIM / BM) * NBN)   // 1376 (divisible by 8)

// LDS per buffer: A 256x64B = 16 KiB, B 256x64B = 16 KiB -> 32 KiB; x2 = 64 KiB.
// 2 blocks/CU (128 KiB LDS total, 16 waves) — LDS-limited, not reg-limited.
#define BUF_STRIDE 32768
#define B_OFF 16384

typedef int int4v __attribute__((ext_vector_type(4)));
typedef int int16v __attribute__((ext_vector_type(16)));

__device__ __forceinline__ void async_copy16(const void* g, void* l) {
  __builtin_amdgcn_global_load_lds(
      (const __attribute__((address_space(1))) void*)g,
      (__attribute__((address_space(3))) void*)l, 16, 0, 0);
}

// ---- x quantization: one block per row; per-row absmax -> i8 ----
__global__ __launch_bounds__(256) void quant_x(const float* __restrict__ x,
                                               signed char* __restrict__ xq,
                                               float* __restrict__ sx) {
  __shared__ float wred[4];
  const int row = blockIdx.x;
  const int tid = threadIdx.x;
  const float4* src = (const float4*)(x + (size_t)row * K_DIM) + tid * 4;
  float4 v0 = src[0], v1 = src[1], v2 = src[2], v3 = src[3];

  float m = 0.f;
#define MX4(V) m = fmaxf(m, fmaxf(fmaxf(fabsf(V.x), fabsf(V.y)), fmaxf(fabsf(V.z), fabsf(V.w))))
  MX4(v0); MX4(v1); MX4(v2); MX4(v3);
#undef MX4
#pragma unroll
  for (int off = 32; off >= 1; off >>= 1)
    m = fmaxf(m, __shfl_xor(m, off, 64));
  if ((tid & 63) == 0) wred[tid >> 6] = m;
  __syncthreads();
  float smax = fmaxf(fmaxf(wred[0], wred[1]), fmaxf(wred[2], wred[3]));
  smax = fmaxf(smax, 1e-20f);
  const float inv = 127.f / smax;

  int4v o;
#define Q4(V, G) o[G] = ((int)rintf(V.x * inv) & 255) | (((int)rintf(V.y * inv) & 255) << 8) | \
                        (((int)rintf(V.z * inv) & 255) << 16) | (((int)rintf(V.w * inv) & 255) << 24)
  Q4(v0, 0); Q4(v1, 1); Q4(v2, 2); Q4(v3, 3);
#undef Q4
  ((int4v*)(xq + (size_t)row * K_DIM))[tid] = o;
  if (tid == 0) sx[row] = smax / 127.f;
}

// ---- W pack: int32 (0..15) -> i8, 16 elems/thread ----
__global__ __launch_bounds__(256) void pack_w(const int* __restrict__ in,
                                              signed char* __restrict__ wq) {
  const int idx = blockIdx.x * 256 + threadIdx.x;
  const int4* in4 = (const int4*)in + (size_t)idx * 4;
  int4 a = in4[0], b = in4[1], c = in4[2], d = in4[3];
  int4v o;
  o[0] = a.x | (a.y << 8) | (a.z << 16) | (a.w << 24);
  o[1] = b.x | (b.y << 8) | (b.z << 16) | (b.w << 24);
  o[2] = c.x | (c.y << 8) | (c.z << 16) | (c.w << 24);
  o[3] = d.x | (d.y << 8) | (d.z << 16) | (d.w << 24);
  ((int4v*)wq)[idx] = o;
}

// Stage one 128x64B group (8 KiB): linear LDS dest, inverse-swizzled global
// source. key(r) = ((r>>1)^(r>>3))&3 on the 16B-chunk index; grow0 is a
// multiple of 128 so key depends only on rl. 1 gload_lds/thread.
__device__ __forceinline__ void stage_q(const signed char* __restrict__ P,
                                        int grow0, int k0b, char* dest, int tid) {
  const int rl = tid >> 2;                           // 0..127
  const int key = ((rl >> 1) ^ (rl >> 3)) & 3;
  const int kb = (((tid & 3) ^ key) << 4);           // pre-swizzled chunk byte
  async_copy16(&P[(size_t)(grow0 + rl) * K_DIM + k0b + kb], dest + tid * 16);
}

// ---- main GEMM: 256x256 block-tile, BKB=64, 8 waves (2x4, 128x64/wave),
// i8 MFMA, 64 KiB LDS => 2 blocks/CU (LDS-limited).
// __launch_bounds__(512,2): cap 256 regs/wave — R13's (512,4) forced a
// 128-reg cap against ~200 needed => total spill (WRITE_SIZE 352K->1.7e7).
// Occupancy needs only the REG POOL (4 waves/SIMD x ~200 = 800 <= 2048),
// not the per-wave cap. R5 sync skeleton unchanged. ----
// C/D: col=lane&31, row=(reg&3)+8*(reg>>2)+4*(lane>>5) [m74/m101; R9-R12 HW-ok].
__global__ __launch_bounds__(512, 2) void gemm_i8(
    const signed char* __restrict__ A, const signed char* __restrict__ B,
    const float* __restrict__ scale, const float* __restrict__ sx,
    float* __restrict__ out) {
  __shared__ __align__(16) char smw[2 * BUF_STRIDE];  // 64 KiB
  const int tid = threadIdx.x;
  const int lane = tid & 63;
  const int wv = tid >> 6;
  const int wr = wv >> 2, wc = wv & 3;   // 2x4 wave grid, 128x64 out/wave
  const int l31 = lane & 31;
  const int h = lane >> 5;
  const int swz = ((((l31 >> 1) ^ (l31 >> 3)) & 3) << 4);  // lane-only key

  int id = blockIdx.x;                   // T1: bijective XCD swizzle
  id = (id & 7) * (NWG / 8) + (id >> 3);
  const int bn = (id % NBN) * BN;
  const int bm = (id / NBN) * BM;

  int16v acc[4][2] = {};                 // 128 accum regs

  // prologue: stage tile 0 (4 issues); vmcnt BEFORE barrier (visibility)
  stage_q(A, bm,       0, smw,                 tid);
  stage_q(A, bm + 128, 0, smw + 8192,          tid);
  stage_q(B, bn,       0, smw + B_OFF,         tid);
  stage_q(B, bn + 128, 0, smw + B_OFF + 8192,  tid);
  asm volatile("s_waitcnt vmcnt(0)" ::: "memory");
  __builtin_amdgcn_s_barrier();

#pragma unroll 1
  for (int t = 0; t < NT; ++t) {
    const int cur = t & 1;
    const char* Abuf = smw + cur * BUF_STRIDE + wr * 8192;   // wave's 128 A-rows
    const char* Bbuf = smw + cur * BUF_STRIDE + B_OFF + (wc >> 1) * 8192;
    char* nb = smw + (cur ^ 1) * BUF_STRIDE;
    const int k1 = (t + 1) * BKB;
    const bool pf = (t + 1 < NT);

    // 2 K-halves; 6 ds_read_b128 + 8 MFMA each; prefetch spread across them
#pragma unroll
    for (int kq = 0; kq < 2; ++kq) {
      const int cb = ((kq * 2 + h) << 4) ^ swz;
      int4v af[4], bfr[2];
#pragma unroll
      for (int mi = 0; mi < 4; ++mi)
        af[mi] = *(const int4v*)(Abuf + (mi * 32 + l31) * 64 + cb);
#pragma unroll
      for (int ni = 0; ni < 2; ++ni)
        bfr[ni] = *(const int4v*)(Bbuf + ((wc & 1) * 64 + ni * 32 + l31) * 64 + cb);
      if (pf) {
        if (kq == 0) {
          stage_q(A, bm,       k1, nb,        tid);
          stage_q(A, bm + 128, k1, nb + 8192, tid);
        } else {
          stage_q(B, bn,       k1, nb + B_OFF,        tid);
          stage_q(B, bn + 128, k1, nb + B_OFF + 8192, tid);
        }
      }
      __builtin_amdgcn_s_setprio(1);
#pragma unroll
      for (int mi = 0; mi < 4; ++mi)
#pragma unroll
        for (int ni = 0; ni < 2; ++ni)
          acc[mi][ni] = __builtin_amdgcn_mfma_i32_32x32x32_i8(
              af[mi], bfr[ni], acc[mi][ni], 0, 0, 0);
      __builtin_amdgcn_s_setprio(0);
    }

    // Bottom sync: drain own prefetch, THEN barrier (cross-wave visibility).
    // Drain gap covered by the co-resident block's compute (R12-verified).
    if (pf) {
      asm volatile("s_waitcnt vmcnt(0)" ::: "memory");
      __builtin_amdgcn_s_barrier();
    }
  }

  // epilogue: y = acc * sx[row] * scale[col]; 32x32 C/D layout
  const int ocol0 = bn + wc * 64 + l31;
  const int orow0 = bm + wr * 128 + 4 * h;
#pragma unroll
  for (int ni = 0; ni < 2; ++ni) {
    const float sc = scale[ocol0 + ni * 32];
#pragma unroll
    for (int mi = 0; mi < 4; ++mi) {
#pragma unroll
      for (int reg = 0; reg < 16; ++reg) {
        const int row = orow0 + mi * 32 + (reg & 3) + 8 * (reg >> 2);
        out[(size_t)row * N_DIM + ocol0 + ni * 32] =
            (float)acc[mi][ni][reg] * sx[row] * sc;
      }
    }
  }
}

// ---- fallback (only if ws too small): fp32 LDS-tiled, correct but slow ----
__global__ __launch_bounds__(256) void gemm_fallback(
    const float* __restrict__ X, const int* __restrict__ Wq,
    const float* __restrict__ scale, float* __restrict__ out) {
  __shared__ float Xs[64][17];
  __shared__ float Ws[64][17];
  const int tid = threadIdx.x;
  const int tn = blockIdx.x % (N_DIM / 64);
  const int tm = blockIdx.x / (N_DIM / 64);
  const int tr = tid >> 4, tc = tid & 15;
  float acc[4][4] = {};
  for (int k0 = 0; k0 < K_DIM; k0 += 16) {
#pragma unroll
    for (int i = 0; i < 4; ++i) {
      int idx = tid + i * 256;
      int r = idx >> 4, c = idx & 15;
      Xs[r][c] = X[(size_t)(tm * 64 + r) * K_DIM + k0 + c];
      Ws[r][c] = (float)Wq[(size_t)(tn * 64 + r) * K_DIM + k0 + c];
    }
    __syncthreads();
#pragma unroll
    for (int kk = 0; kk < 16; ++kk)
#pragma unroll
      for (int i = 0; i < 4; ++i) {
        float a = Xs[tr * 4 + i][kk];
#pragma unroll
        for (int j = 0; j < 4; ++j) acc[i][j] += a * Ws[tc * 4 + j][kk];
      }
    __syncthreads();
  }
#pragma unroll
  for (int i = 0; i < 4; ++i)
#pragma unroll
    for (int j = 0; j < 4; ++j) {
      int row = tm * 64 + tr * 4 + i, col = tn * 64 + tc * 4 + j;
      out[(size_t)row * N_DIM + col] = acc[i][j] * scale[col];
    }
}

extern "C" void kernel_launch(void* const* d_in, const int* in_sizes, int n_in,
                              void* d_out, int out_size, void* d_ws, size_t ws_size,
                              hipStream_t stream) {
  const float* x = (const float*)d_in[0];
  const int* Wq = (const int*)d_in[1];
  const float* scale = (const float*)d_in[2];
  float* out = (float*)d_out;

  const size_t XN = (size_t)M_DIM * K_DIM;   // 33,554,432
  const size_t WN = (size_t)N_DIM * K_DIM;   // 45,088,768
  const size_t need = XN + WN + M_DIM * sizeof(float);

  if (ws_size >= need) {
    signed char* xq = (signed char*)d_ws;
    signed char* wq = xq + XN;
    float* sx = (float*)(wq + WN);
    quant_x<<<M_DIM, 256, 0, stream>>>(x, xq, sx);
    pack_w<<<(unsigned)(WN / 4096), 256, 0, stream>>>(Wq, wq);
    gemm_i8<<<NWG, 512, 0, stream>>>(xq, wq, scale, sx, out);
  } else {
    gemm_fallback<<<(N_DIM / 64) * (M_DIM / 64), 256, 0, stream>>>(x, Wq, scale, out);
  }
}

// Round 15
// 494.019 us; speedup vs baseline: 12.8891x; 1.0431x over previous
//
#include <hip/hip_runtime.h>
#include <math.h>

// QLinear via int8: y = (sum_k xq[r][k]*Wq[c][k]) * sx[r] * scale[c]
// Wq in [0,16) is EXACT in i8; only x-quantization contributes error.
#define M_DIM 8192    // BATCH*SEQ
#define N_DIM 11008   // OUT_F
#define K_DIM 4096    // IN_F

#define BM 256
#define BN 128
#define BKB 128                    // K-bytes per tile (128 i8 -> 128-B LDS rows)
#define NT (K_DIM / BKB)           // 32 K-tiles
#define NBN (N_DIM / BN)           // 86
#define NWG ((M_DIM / BM) * NBN)   // 32*86 = 2752 (divisible by 8)

// Single buffer: A 256x128B = 32 KiB, B 128x128B = 16 KiB -> 48 KiB.
// 2 blocks/CU (96 KiB LDS, 16 waves; regs ~110 -> 4 waves/SIMD fits 512 pool).
#define B_OFF 32768

typedef int int4v __attribute__((ext_vector_type(4)));
typedef int int16v __attribute__((ext_vector_type(16)));

__device__ __forceinline__ void async_copy16(const void* g, void* l) {
  __builtin_amdgcn_global_load_lds(
      (const __attribute__((address_space(1))) void*)g,
      (__attribute__((address_space(3))) void*)l, 16, 0, 0);
}

// ---- x quantization: one block per row; per-row absmax -> i8 ----
__global__ __launch_bounds__(256) void quant_x(const float* __restrict__ x,
                                               signed char* __restrict__ xq,
                                               float* __restrict__ sx) {
  __shared__ float wred[4];
  const int row = blockIdx.x;
  const int tid = threadIdx.x;
  const float4* src = (const float4*)(x + (size_t)row * K_DIM) + tid * 4;
  float4 v0 = src[0], v1 = src[1], v2 = src[2], v3 = src[3];

  float m = 0.f;
#define MX4(V) m = fmaxf(m, fmaxf(fmaxf(fabsf(V.x), fabsf(V.y)), fmaxf(fabsf(V.z), fabsf(V.w))))
  MX4(v0); MX4(v1); MX4(v2); MX4(v3);
#undef MX4
#pragma unroll
  for (int off = 32; off >= 1; off >>= 1)
    m = fmaxf(m, __shfl_xor(m, off, 64));
  if ((tid & 63) == 0) wred[tid >> 6] = m;
  __syncthreads();
  float smax = fmaxf(fmaxf(wred[0], wred[1]), fmaxf(wred[2], wred[3]));
  smax = fmaxf(smax, 1e-20f);
  const float inv = 127.f / smax;

  int4v o;
#define Q4(V, G) o[G] = ((int)rintf(V.x * inv) & 255) | (((int)rintf(V.y * inv) & 255) << 8) | \
                        (((int)rintf(V.z * inv) & 255) << 16) | (((int)rintf(V.w * inv) & 255) << 24)
  Q4(v0, 0); Q4(v1, 1); Q4(v2, 2); Q4(v3, 3);
#undef Q4
  ((int4v*)(xq + (size_t)row * K_DIM))[tid] = o;
  if (tid == 0) sx[row] = smax / 127.f;
}

// ---- W pack: int32 (0..15) -> i8, 16 elems/thread ----
__global__ __launch_bounds__(256) void pack_w(const int* __restrict__ in,
                                              signed char* __restrict__ wq) {
  const int idx = blockIdx.x * 256 + threadIdx.x;
  const int4* in4 = (const int4*)in + (size_t)idx * 4;
  int4 a = in4[0], b = in4[1], c = in4[2], d = in4[3];
  int4v o;
  o[0] = a.x | (a.y << 8) | (a.z << 16) | (a.w << 24);
  o[1] = b.x | (b.y << 8) | (b.z << 16) | (b.w << 24);
  o[2] = c.x | (c.y << 8) | (c.z << 16) | (c.w << 24);
  o[3] = d.x | (d.y << 8) | (d.z << 16) | (d.w << 24);
  ((int4v*)wq)[idx] = o;
}

// Stage one 64-row x 128-B group (8 KiB): linear LDS dest, inverse-swizzled
// global source (rule #21). 128-B rows -> 8 16-B chunks; key(r) =
// (r&7)^((r>>4)&1) — the R10-validated zero-conflict 3-bit key.
// 1 gload_lds/thread per call (512 thr x 16 B = 8 KiB).
__device__ __forceinline__ void stage_g(const signed char* __restrict__ P,
                                        int grow0, int k0b, char* dest, int tid) {
  const int r = tid >> 3;                             // 0..63
  const int key = (r & 7) ^ ((tid >> 7) & 1);         // (r>>4)&1 == (tid>>7)&1
  const int c = (tid & 7) ^ key;                      // pre-swizzled chunk
  async_copy16(&P[(size_t)(grow0 + r) * K_DIM + k0b + c * 16], dest + tid * 16);
}

// ---- main GEMM: 256x128 block-tile, BKB=128, 8 waves (4x2, 64x64/wave),
// SINGLE 48-KiB buffer, 2 blocks/CU. Per K-tile:
//   barrier (readers of t-1 done) -> stage 6 groups -> vmcnt(0) -> barrier
//   -> 4 k-steps of {4 ds_read_b128 + 4 MFMA}.
// The fill stall is covered by the co-resident block's compute phase.
// 128-B rows + 3-bit XOR key = zero bank conflicts (R10-measured).
// C/D: col=lane&31, row=(reg&3)+8*(reg>>2)+4*(lane>>5) [m74/m101; R9-R14 HW-ok].
__global__ __launch_bounds__(512, 2) void gemm_i8(
    const signed char* __restrict__ A, const signed char* __restrict__ B,
    const float* __restrict__ scale, const float* __restrict__ sx,
    float* __restrict__ out) {
  __shared__ __align__(16) char smw[49152];  // 48 KiB, single buffer
  const int tid = threadIdx.x;
  const int lane = tid & 63;
  const int wv = tid >> 6;
  const int wr = wv >> 1, wc = wv & 1;   // 4x2 wave grid, 64x64 out/wave
  const int l31 = lane & 31;
  const int h = lane >> 5;
  const int swz = (l31 & 7) ^ ((l31 >> 4) & 1);  // read-side 3-bit key

  int id = blockIdx.x;                   // T1: bijective XCD swizzle
  id = (id & 7) * (NWG / 8) + (id >> 3);
  const int bn = (id % NBN) * BN;
  const int bm = (id / NBN) * BM;

  int16v acc[2][2] = {};                 // 64 accum regs

#pragma unroll 1
  for (int t = 0; t < NT; ++t) {
    const int kb = t * BKB;
    __builtin_amdgcn_s_barrier();        // all reads of tile t-1 retired (WAR)
    stage_g(A, bm,       kb, smw,         tid);
    stage_g(A, bm + 64,  kb, smw +  8192, tid);
    stage_g(A, bm + 128, kb, smw + 16384, tid);
    stage_g(A, bm + 192, kb, smw + 24576, tid);
    stage_g(B, bn,       kb, smw + B_OFF,        tid);
    stage_g(B, bn + 64,  kb, smw + B_OFF + 8192, tid);
    asm volatile("s_waitcnt vmcnt(0)" ::: "memory");  // BEFORE barrier
    __builtin_amdgcn_s_barrier();        // tile t visible to all waves

    // 4 k-steps of 32 B; reads chunk (2ks+h)^key; compiler pipelines
#pragma unroll
    for (int ks = 0; ks < 4; ++ks) {
      const int cb = ((2 * ks + h) ^ swz) * 16;
      int4v af[2], bfr[2];
#pragma unroll
      for (int mi = 0; mi < 2; ++mi)
        af[mi] = *(const int4v*)(smw + (wr * 64 + mi * 32 + l31) * 128 + cb);
#pragma unroll
      for (int ni = 0; ni < 2; ++ni)
        bfr[ni] = *(const int4v*)(smw + B_OFF + (wc * 64 + ni * 32 + l31) * 128 + cb);
      __builtin_amdgcn_s_setprio(1);
#pragma unroll
      for (int mi = 0; mi < 2; ++mi)
#pragma unroll
        for (int ni = 0; ni < 2; ++ni)
          acc[mi][ni] = __builtin_amdgcn_mfma_i32_32x32x32_i8(
              af[mi], bfr[ni], acc[mi][ni], 0, 0, 0);
      __builtin_amdgcn_s_setprio(0);
    }
  }

  // epilogue: y = acc * sx[row] * scale[col]; 32x32 C/D layout
  const int ocol0 = bn + wc * 64 + l31;
  const int orow0 = bm + wr * 64 + 4 * h;
#pragma unroll
  for (int ni = 0; ni < 2; ++ni) {
    const float sc = scale[ocol0 + ni * 32];
#pragma unroll
    for (int mi = 0; mi < 2; ++mi) {
#pragma unroll
      for (int reg = 0; reg < 16; ++reg) {
        const int row = orow0 + mi * 32 + (reg & 3) + 8 * (reg >> 2);
        out[(size_t)row * N_DIM + ocol0 + ni * 32] =
            (float)acc[mi][ni][reg] * sx[row] * sc;
      }
    }
  }
}

// ---- fallback (only if ws too small): fp32 LDS-tiled, correct but slow ----
__global__ __launch_bounds__(256) void gemm_fallback(
    const float* __restrict__ X, const int* __restrict__ Wq,
    const float* __restrict__ scale, float* __restrict__ out) {
  __shared__ float Xs[64][17];
  __shared__ float Ws[64][17];
  const int tid = threadIdx.x;
  const int tn = blockIdx.x % (N_DIM / 64);
  const int tm = blockIdx.x / (N_DIM / 64);
  const int tr = tid >> 4, tc = tid & 15;
  float acc[4][4] = {};
  for (int k0 = 0; k0 < K_DIM; k0 += 16) {
#pragma unroll
    for (int i = 0; i < 4; ++i) {
      int idx = tid + i * 256;
      int r = idx >> 4, c = idx & 15;
      Xs[r][c] = X[(size_t)(tm * 64 + r) * K_DIM + k0 + c];
      Ws[r][c] = (float)Wq[(size_t)(tn * 64 + r) * K_DIM + k0 + c];
    }
    __syncthreads();
#pragma unroll
    for (int kk = 0; kk < 16; ++kk)
#pragma unroll
      for (int i = 0; i < 4; ++i) {
        float a = Xs[tr * 4 + i][kk];
#pragma unroll
        for (int j = 0; j < 4; ++j) acc[i][j] += a * Ws[tc * 4 + j][kk];
      }
    __syncthreads();
  }
#pragma unroll
  for (int i = 0; i < 4; ++i)
#pragma unroll
    for (int j = 0; j < 4; ++j) {
      int row = tm * 64 + tr * 4 + i, col = tn * 64 + tc * 4 + j;
      out[(size_t)row * N_DIM + col] = acc[i][j] * scale[col];
    }
}

extern "C" void kernel_launch(void* const* d_in, const int* in_sizes, int n_in,
                              void* d_out, int out_size, void* d_ws, size_t ws_size,
                              hipStream_t stream) {
  const float* x = (const float*)d_in[0];
  const int* Wq = (const int*)d_in[1];
  const float* scale = (const float*)d_in[2];
  float* out = (float*)d_out;

  const size_t XN = (size_t)M_DIM * K_DIM;   // 33,554,432
  const size_t WN = (size_t)N_DIM * K_DIM;   // 45,088,768
  const size_t need = XN + WN + M_DIM * sizeof(float);

  if (ws_size >= need) {
    signed char* xq = (signed char*)d_ws;
    signed char* wq = xq + XN;
    float* sx = (float*)(wq + WN);
    quant_x<<<M_DIM, 256, 0, stream>>>(x, xq, sx);
    pack_w<<<(unsigned)(WN / 4096), 256, 0, stream>>>(Wq, wq);
    gemm_i8<<<NWG, 512, 0, stream>>>(xq, wq, scale, sx, out);
  } else {
    gemm_fallback<<<(N_DIM / 64) * (M_DIM / 64), 256, 0, stream>>>(x, Wq, scale, out);
  }
}